// Round 5
// baseline (160.212 us; speedup 1.0000x reference)
//
#include <hip/hip_runtime.h>
#include <cfloat>

// Problem constants: M=N=64 grid, DIM=512, B=4096, SIGMA=32
#define DIMK 512
#define MN   4096
#define BATCH 4096
#define NGRP 1024   // 4-column groups per row

typedef _Float16 half8_t __attribute__((ext_vector_type(8)));
typedef _Float16 half4_t __attribute__((ext_vector_type(4)));
typedef float f32x4 __attribute__((ext_vector_type(4)));

// ---------------------------------------------------------------------------
// Convert: X,W fp32 -> f16 RTN + exact fp32 row norms. (unchanged)
// ---------------------------------------------------------------------------
__global__ __launch_bounds__(256) void convert_kernel(
        const float* __restrict__ X, const float* __restrict__ W,
        _Float16* __restrict__ Xh, _Float16* __restrict__ Wh,
        float* __restrict__ w2, float* __restrict__ xnorm) {
    const int blk  = blockIdx.x;
    const int t    = threadIdx.x;
    const bool isW = blk >= 1024;
    const float* src = isW ? W : X;
    _Float16* dst  = isW ? Wh : Xh;
    const int rblk = isW ? blk - 1024 : blk;
    const size_t idx = (size_t)rblk * 2048 + (size_t)t * 8;

    float4 v0 = *(const float4*)(src + idx);
    float4 v1 = *(const float4*)(src + idx + 4);
    float v[8] = {v0.x, v0.y, v0.z, v0.w, v1.x, v1.y, v1.z, v1.w};
    half8_t hv;
    float s = 0.f;
#pragma unroll
    for (int e = 0; e < 8; e++) {
        s += v[e] * v[e];
        hv[e] = (_Float16)v[e];
    }
    *(half8_t*)(dst + idx) = hv;
#pragma unroll
    for (int o = 32; o > 0; o >>= 1) s += __shfl_down(s, o);
    if ((t & 63) == 0) {
        int row = rblk * 4 + (t >> 6);
        if (isW) w2[row] = s;
        else     xnorm[row] = __fsqrt_rn(s);
    }
}

// ---------------------------------------------------------------------------
// Score GEMM v5: LDS-FREE, BARRIER-FREE. 256x128 tile, 4 waves (2m x 2n),
// each wave owns a 128x64 output and loads its MFMA fragments DIRECTLY from
// global (L2-resident, 8MB total) into registers: 12 global_load_dwordx4
// per K-tile, 2-deep register pipeline, counted s_waitcnt vmcnt(12) (never
// 0 until the last tile). Zero __syncthreads, zero LDS, zero
// global_load_lds -> no staging-DMA serialization, no barrier coupling;
// waves drift freely, 2 blocks/CU co-resident. Per-XCD swizzle rect =
// 4(bm) x 16(bn) -> working set A 1MB + B 2MB = 3MB < 4MB L2.
// Fragment positions and K-accumulation order identical to all prior
// rounds -> bit-identical group-mins -> screen margins unchanged.
// ---------------------------------------------------------------------------
__global__ __launch_bounds__(256, 2) void score_kernel(
        const _Float16* __restrict__ Xh, const _Float16* __restrict__ Wh,
        const float* __restrict__ w2, _Float16* __restrict__ Gm) {
    const int t    = threadIdx.x;
    const int lane = t & 63;
    const int w    = t >> 6;        // wave 0..3
    const int wm   = w >> 1;        // m-half (0..1) -> 128 rows
    const int wn   = w & 1;         // n-half (0..1) -> 64 cols

    // swizzle: 512 blocks, 8 XCDs x 64; each XCD a 4(bm) x 16(bn) rect.
    const int id  = blockIdx.y * 32 + blockIdx.x;   // gridDim = (32,16)
    const int xcd = id & 7;
    const int li  = id >> 3;                 // 0..63
    const int bm  = (xcd >> 1) * 4 + (li >> 4);     // 0..15 (256-row tiles)
    const int bn  = (xcd & 1) * 16 + (li & 15);     // 0..31 (128-col tiles)
    const int m0  = bm * 256;
    const int n0  = bn * 128;

    // per-lane fragment element offsets (f16 units): frag(rg): lane reads
    // row rg*16 + (lane&15), k-bytes (lane>>4)*8 within the 32-wide K slice.
    const int r16 = lane & 15;
    const int k8  = (lane >> 4) * 8;
    const int offA = (m0 + wm * 128 + r16) * DIMK + k8;
    const int offB = (n0 + wn * 64  + r16) * DIMK + k8;

    f32x4 acc[8][4];
#pragma unroll
    for (int i = 0; i < 8; i++)
#pragma unroll
        for (int j = 0; j < 4; j++) acc[i][j] = (f32x4){0.f, 0.f, 0.f, 0.f};

    half8_t a[2][8], b[2][4];

    // stage 0: tile 0's 12 fragment loads
#pragma unroll
    for (int i = 0; i < 8; i++)
        a[0][i] = *(const half8_t*)(Xh + offA + i * (16 * DIMK));
#pragma unroll
    for (int j = 0; j < 4; j++)
        b[0][j] = *(const half8_t*)(Wh + offB + j * (16 * DIMK));

#pragma unroll
    for (int kt = 0; kt < 16; ++kt) {
        const int cur = kt & 1;
        const int nxt = cur ^ 1;
        if (kt < 15) {
            const int ko = (kt + 1) * 32;
#pragma unroll
            for (int i = 0; i < 8; i++)
                a[nxt][i] = *(const half8_t*)(Xh + offA + i * (16 * DIMK) + ko);
#pragma unroll
            for (int j = 0; j < 4; j++)
                b[nxt][j] = *(const half8_t*)(Wh + offB + j * (16 * DIMK) + ko);
            // wait tile kt's 12 loads (oldest); keep kt+1's 12 in flight
            asm volatile("s_waitcnt vmcnt(12)" ::: "memory");
        } else {
            asm volatile("s_waitcnt vmcnt(0)" ::: "memory");
        }
        __builtin_amdgcn_sched_barrier(0);
        __builtin_amdgcn_s_setprio(1);
#pragma unroll
        for (int i = 0; i < 8; i++)
#pragma unroll
            for (int j = 0; j < 4; j++)
                acc[i][j] = __builtin_amdgcn_mfma_f32_16x16x32_f16(
                    a[cur][i], b[cur][j], acc[i][j], 0, 0, 0);
        __builtin_amdgcn_s_setprio(0);
    }

    // ---- 4-col group mins -> f16, packed 1024/row (verified layout).
    // D layout: col=lane&15, row=(lane>>4)*4+v ----
    const int q   = lane >> 4;
    const int cl  = lane & 15;
    const int gb  = (n0 >> 2) + wn * 16;
    float w2v[4];
#pragma unroll
    for (int j = 0; j < 4; j++) w2v[j] = w2[n0 + wn * 64 + j * 16 + cl];
#pragma unroll
    for (int ai = 0; ai < 8; ai++)
#pragma unroll
        for (int v = 0; v < 4; v++) {
            const int row = m0 + wm * 128 + ai * 16 + q * 4 + v;
            _Float16* grow = Gm + (size_t)row * 1024 + gb;
#pragma unroll
            for (int j = 0; j < 4; j++) {
                float s = w2v[j] - 2.0f * acc[ai][j][v];
                s = fminf(s, __shfl_xor(s, 1));
                s = fminf(s, __shfl_xor(s, 2));
                if ((cl & 3) == 0) grow[j * 4 + (cl >> 2)] = (_Float16)s;
            }
        }
}

// ---------------------------------------------------------------------------
// Fused epilogue: f16 group-min screen + 4-col-concurrent exact fp32 rescore
// (16 lanes/col, coalesced float4 W reads, order-preserving u64 min key)
// + uniform merge + separable Gaussian row write. (unchanged from R4)
// ---------------------------------------------------------------------------
__global__ __launch_bounds__(256) void epilogue_kernel(
        const float* __restrict__ w2, const float* __restrict__ xnorm,
        const float* __restrict__ X, const float* __restrict__ W,
        const _Float16* __restrict__ gm,
        const int* __restrict__ decay_p, const int* __restrict__ it_p,
        float* __restrict__ out) {
    __shared__ float xs[512];
    __shared__ int   list[NGRP];
    __shared__ int   cnt;
    __shared__ float wmin[4];
    __shared__ unsigned long long wkey[4];
    __shared__ float tab[128];
    const int row  = blockIdx.x;
    const int t    = threadIdx.x;
    const int lane = t & 63;
    const int w    = t >> 6;

    {
        float2 xv = *(const float2*)(X + (size_t)row * DIMK + t * 2);
        xs[2 * t]     = xv.x;
        xs[2 * t + 1] = xv.y;
    }
    if (t == 0) cnt = 0;

    // f16 group-mins: 4 per thread (8B coalesced), packed 2KB/row
    half4_t gmh = *((const half4_t*)(gm + (size_t)row * 1024) + t);
    float gme[4] = {(float)gmh[0], (float)gmh[1], (float)gmh[2], (float)gmh[3]};
    float g = fminf(fminf(gme[0], gme[1]), fminf(gme[2], gme[3]));
#pragma unroll
    for (int mask = 1; mask <= 32; mask <<= 1)
        g = fminf(g, __shfl_xor(g, mask));
    if (lane == 0) wmin[w] = g;
    __syncthreads();
    const float gmin = fminf(fminf(wmin[0], wmin[1]), fminf(wmin[2], wmin[3]));
    const float tau  = gmin + 2.0f * (0.0222f * xnorm[row] + 0.25f);

#pragma unroll
    for (int e = 0; e < 4; e++)
        if (gme[e] <= tau) list[atomicAdd(&cnt, 1)] = t * 4 + e;
    __syncthreads();
    const int total = cnt;            // >= 1 always (gmin's group qualifies)

    // preload this lane's x-slice: float4 elems e*16 + s16, e = 0..7
    const int s16 = lane & 15;
    const int cg  = lane >> 4;        // column-in-group this lane serves
    float4 xq[8];
#pragma unroll
    for (int e = 0; e < 8; e++) xq[e] = ((const float4*)xs)[e * 16 + s16];

    unsigned long long mkey = ~0ULL;
    for (int idx = w; idx < total; idx += 4) {
        const int col = list[idx] * 4 + cg;
        const float4* wr = (const float4*)(W + (size_t)col * DIMK);
        float p = 0.f;
#pragma unroll
        for (int e = 0; e < 8; e++) {
            float4 wv = wr[e * 16 + s16];   // 16 lanes x 16B contiguous / col
            p += xq[e].x * wv.x + xq[e].y * wv.y
               + xq[e].z * wv.z + xq[e].w * wv.w;
        }
        p += __shfl_xor(p, 1); p += __shfl_xor(p, 2);
        p += __shfl_xor(p, 4); p += __shfl_xor(p, 8);
        const float s = w2[col] - 2.0f * p;
        unsigned int b = __float_as_uint(s);
        unsigned int u = (b & 0x80000000u) ? ~b : (b | 0x80000000u);
        unsigned long long key = ((unsigned long long)u << 32) | (unsigned int)col;
        mkey = key < mkey ? key : mkey;
    }
    {   // fold the 4 column-sets (lane bits 4,5)
        unsigned long long o;
        o = __shfl_xor(mkey, 16); mkey = o < mkey ? o : mkey;
        o = __shfl_xor(mkey, 32); mkey = o < mkey ? o : mkey;
    }
    if (lane == 0) wkey[w] = mkey;
    __syncthreads();
    // uniform merge: every thread computes the same winner
    unsigned long long k = wkey[0];
#pragma unroll
    for (int i = 1; i < 4; i++) k = wkey[i] < k ? wkey[i] : k;
    const int sbi = (int)(k & 0xffffffffu);

    // separable Gaussian tables + row write
    const float lr  = __expf(-(float)(*it_p) / (float)(*decay_p));
    const float so  = 32.0f * lr;          // SIGMA = 32
    const float inv = 1.0f / (so * so);
    const int rr = sbi >> 6, cc = sbi & 63;
    if (t < 64) {
        float d = (float)(t - rr);
        tab[t] = __expf(-d * d * inv);
    } else if (t < 128) {
        float d = (float)(t - 64 - cc);
        tab[t] = __expf(-d * d * inv);
    }
    __syncthreads();
    const float* er = tab;
    const float* ec = tab + 64;
    f32x4* orow = (f32x4*)(out + (size_t)row * 4096);
#pragma unroll
    for (int qq = 0; qq < 4; qq++) {
        int f  = qq * 256 + t;
        int i  = f >> 4;
        int j0 = (f & 15) * 4;
        float e = er[i];
        f32x4 o = {e * ec[j0], e * ec[j0 + 1], e * ec[j0 + 2], e * ec[j0 + 3]};
        __builtin_nontemporal_store(o, orow + f);
    }
}

// ---------------------------------------------------------------------------
extern "C" void kernel_launch(void* const* d_in, const int* in_sizes, int n_in,
                              void* d_out, int out_size, void* d_ws, size_t ws_size,
                              hipStream_t stream) {
    const float* X       = (const float*)d_in[0];   // [4096,512]
    const float* W       = (const float*)d_in[1];   // [4096,512]
    const int*   decay_p = (const int*)d_in[3];
    const int*   it_p    = (const int*)d_in[4];
    float* out = (float*)d_out;

    // ws: Xh 4MB | Wh 4MB | w2 16KB | xnorm 16KB | gmins 8MB
    _Float16* Xh = (_Float16*)d_ws;
    _Float16* Wh = Xh + (size_t)BATCH * DIMK;
    float*    w2 = (float*)(Wh + (size_t)MN * DIMK);
    float*    xn = w2 + MN;
    _Float16* gmv = (_Float16*)(xn + BATCH);

    convert_kernel<<<2048, 256, 0, stream>>>(X, W, Xh, Wh, w2, xn);
    score_kernel<<<dim3(32, 16), 256, 0, stream>>>(Xh, Wh, w2, gmv);
    epilogue_kernel<<<BATCH, 256, 0, stream>>>(w2, xn, X, W, gmv, decay_p, it_p, out);
}

// Round 6
// 133.975 us; speedup vs baseline: 1.1958x; 1.1958x over previous
//
#include <hip/hip_runtime.h>
#include <cfloat>

// Problem constants: M=N=64 grid, DIM=512, B=4096, SIGMA=32
#define DIMK 512
#define MN   4096
#define BATCH 4096
#define NGRP 1024   // 4-column groups per row

typedef _Float16 half8_t __attribute__((ext_vector_type(8)));
typedef _Float16 half4_t __attribute__((ext_vector_type(4)));
typedef float f32x4 __attribute__((ext_vector_type(4)));

// async global->LDS, 16B per lane; LDS dest is wave-uniform base + lane*16
#define GLD16(gp, lp) __builtin_amdgcn_global_load_lds( \
    (const __attribute__((address_space(1))) void*)(gp), \
    (__attribute__((address_space(3))) void*)(lp), 16, 0, 0)

// ---------------------------------------------------------------------------
// Convert: X,W fp32 -> f16 RTN + exact fp32 row norms. (unchanged)
// ---------------------------------------------------------------------------
__global__ __launch_bounds__(256) void convert_kernel(
        const float* __restrict__ X, const float* __restrict__ W,
        _Float16* __restrict__ Xh, _Float16* __restrict__ Wh,
        float* __restrict__ w2, float* __restrict__ xnorm) {
    const int blk  = blockIdx.x;
    const int t    = threadIdx.x;
    const bool isW = blk >= 1024;
    const float* src = isW ? W : X;
    _Float16* dst  = isW ? Wh : Xh;
    const int rblk = isW ? blk - 1024 : blk;
    const size_t idx = (size_t)rblk * 2048 + (size_t)t * 8;

    float4 v0 = *(const float4*)(src + idx);
    float4 v1 = *(const float4*)(src + idx + 4);
    float v[8] = {v0.x, v0.y, v0.z, v0.w, v1.x, v1.y, v1.z, v1.w};
    half8_t hv;
    float s = 0.f;
#pragma unroll
    for (int e = 0; e < 8; e++) {
        s += v[e] * v[e];
        hv[e] = (_Float16)v[e];
    }
    *(half8_t*)(dst + idx) = hv;
#pragma unroll
    for (int o = 32; o > 0; o >>= 1) s += __shfl_down(s, o);
    if ((t & 63) == 0) {
        int row = rblk * 4 + (t >> 6);
        if (isW) w2[row] = s;
        else     xnorm[row] = __fsqrt_rn(s);
    }
}

// ---------------------------------------------------------------------------
// Score GEMM v6: COALESCED staging + swizzled row-major LDS.
// 128x128 tile, 4 waves (2m x 2n), BK=32, 4-deep ring (4 x 16 KiB = 64 KiB,
// 2 blocks/CU). Staging: one gld_lds = 16 rows x 64B, lanes 0-3 read
// CONTIGUOUS 64B of one row -> 16 cache lines/instr (vs 64 for the
// fragment-scattered pattern of R0-R5 — the measured limiter). LDS is
// row-major [128 rows][32 f16] per region with chunk-swizzle
// chunk ^= (row>>1)&3 applied on BOTH sides (pre-swizzled global source +
// swizzled ds_read addr; linear gld_lds dest — rule #21). Fragment reads
// then hit the m134 conflict-free-baseline bank pattern. Ring discipline =
// R2/R4's proven single-barrier + counted vmcnt(8). Per-lane MFMA inputs
// bit-identical to all prior rounds -> bit-identical group-mins.
// ---------------------------------------------------------------------------
__global__ __launch_bounds__(256, 2) void score_kernel(
        const _Float16* __restrict__ Xh, const _Float16* __restrict__ Wh,
        const float* __restrict__ w2, _Float16* __restrict__ Gm) {
    // slot = [A 4096 f16 (128 rows x 32)][B 4096] = 16 KiB; ring of 4.
    __shared__ __align__(16) _Float16 lds[4][8192];

    const int t    = threadIdx.x;
    const int lane = t & 63;
    const int w    = t >> 6;        // wave 0..3
    const int wm   = w >> 1;        // m-half (0..1) -> 64 rows
    const int wn   = w & 1;         // n-half (0..1) -> 64 cols

    // bijective XCD swizzle: 1024 blocks, 8 XCDs x 128; per XCD an
    // 8(bm) x 16(bn) rect -> working set A 1MB + B 2MB = 3MB < 4MB L2.
    const int id  = blockIdx.y * 32 + blockIdx.x;   // gridDim (32,32)
    const int xcd = id & 7;
    const int li  = id >> 3;                        // 0..127
    const int bm  = (xcd >> 1) * 8 + (li >> 4);     // 0..31
    const int bn  = (xcd & 1) * 16 + (li & 15);     // 0..31
    const int m0  = bm * 128;
    const int n0  = bn * 128;

    const _Float16* gA = Xh + (size_t)m0 * DIMK;
    const _Float16* gB = Wh + (size_t)n0 * DIMK;

    // staging source (per-lane, f16 units): row-in-group = lane>>2,
    // source chunk = (lane&3) ^ x(row), x(row) = ((lane>>2)>>1)&3 = (lane>>3)&3.
    // Lanes 0-3 read contiguous 64B of one row (permuted 16B chunks).
    const int soff = (lane >> 2) * DIMK + (((lane & 3) ^ ((lane >> 3) & 3)) * 8);

    // STG(reg, rb, kt, sl): stage rows [rb, rb+16) of region reg, k-slice kt,
    // into ring slot sl. LDS dest is wave-uniform (HW adds lane*16B).
#define STG(reg, rb, kt, sl) GLD16( \
    ((reg) ? gB : gA) + (size_t)(rb) * DIMK + (kt) * 32 + soff, \
    &lds[sl][(reg) * 4096 + (rb) * 32])

    // fragment ds_read addr: row = half*64 + rg*16 + r16, chunk = kg ^ x(row);
    // x(row) reduces to (r16>>1)&3 (half*64, rg*16 are 0 mod the XOR period).
    const int r16 = lane & 15;
    const int kg  = lane >> 4;
    const int xx  = (r16 >> 1) & 3;
    const int aoff =        wm * 2048 + r16 * 32 + ((kg ^ xx) * 8);
    const int boff = 4096 + wn * 2048 + r16 * 32 + ((kg ^ xx) * 8);

#define LDA(sl, rg) (*(const half8_t*)(&lds[sl][aoff + (rg) * 512]))
#define LDB(sl, rg) (*(const half8_t*)(&lds[sl][boff + (rg) * 512]))

    f32x4 acc[4][4];
#pragma unroll
    for (int i = 0; i < 4; i++)
#pragma unroll
        for (int j = 0; j < 4; j++) acc[i][j] = (f32x4){0.f, 0.f, 0.f, 0.f};

    const int w32 = w * 32;
    // prologue: stage tiles 0,1,2 into slots 0,1,2 (12 instrs per wave)
#pragma unroll
    for (int pt = 0; pt < 3; ++pt) {
        STG(0, w32,      pt, pt);
        STG(0, w32 + 16, pt, pt);
        STG(1, w32,      pt, pt);
        STG(1, w32 + 16, pt, pt);
    }

#pragma unroll
    for (int kt = 0; kt < 16; ++kt) {
        const int sl = kt & 3;
        const int nb = (kt + 3) & 3;

        // gate: drain this wave's 4 tile-kt loads (issued 3 tiles ago).
        // Outstanding at entry: tiles kt..kt+2 = 12 (kt<=13).
        if (kt <= 13)      { asm volatile("s_waitcnt vmcnt(8)" ::: "memory"); }
        else if (kt == 14) { asm volatile("s_waitcnt vmcnt(4)" ::: "memory"); }
        else               { asm volatile("s_waitcnt vmcnt(0)" ::: "memory"); }
        __builtin_amdgcn_sched_barrier(0);
        __builtin_amdgcn_s_barrier();   // all waves: tile kt landed; all
                                        // reads of slot (kt-1)&3 = nb done.

        if (kt <= 12) {
            STG(0, w32,      kt + 3, nb);
            STG(0, w32 + 16, kt + 3, nb);
            STG(1, w32,      kt + 3, nb);
            STG(1, w32 + 16, kt + 3, nb);
        }

        half8_t a0 = LDA(sl, 0), a1 = LDA(sl, 1);
        half8_t a2 = LDA(sl, 2), a3 = LDA(sl, 3);
        half8_t b0 = LDB(sl, 0), b1 = LDB(sl, 1);
        half8_t b2 = LDB(sl, 2), b3 = LDB(sl, 3);

        asm volatile("s_waitcnt lgkmcnt(0)" ::: "memory");
        __builtin_amdgcn_sched_barrier(0);
        __builtin_amdgcn_s_setprio(1);
#pragma unroll
        for (int i = 0; i < 4; i++) {
            half8_t av = (i == 0) ? a0 : (i == 1) ? a1 : (i == 2) ? a2 : a3;
            acc[i][0] = __builtin_amdgcn_mfma_f32_16x16x32_f16(av, b0, acc[i][0], 0, 0, 0);
            acc[i][1] = __builtin_amdgcn_mfma_f32_16x16x32_f16(av, b1, acc[i][1], 0, 0, 0);
            acc[i][2] = __builtin_amdgcn_mfma_f32_16x16x32_f16(av, b2, acc[i][2], 0, 0, 0);
            acc[i][3] = __builtin_amdgcn_mfma_f32_16x16x32_f16(av, b3, acc[i][3], 0, 0, 0);
        }
        __builtin_amdgcn_s_setprio(0);
    }

    // ---- 4-col group mins -> f16, packed 1024/row (verified layout).
    // D layout: col=lane&15, row=(lane>>4)*4+v ----
    const int q   = lane >> 4;
    const int cl  = lane & 15;
    const int gb  = (n0 >> 2) + wn * 16;
    float w2v[4];
#pragma unroll
    for (int j = 0; j < 4; j++) w2v[j] = w2[n0 + wn * 64 + j * 16 + cl];
#pragma unroll
    for (int i = 0; i < 4; i++)
#pragma unroll
        for (int v = 0; v < 4; v++) {
            const int row = m0 + wm * 64 + i * 16 + q * 4 + v;
            _Float16* grow = Gm + (size_t)row * 1024 + gb;
#pragma unroll
            for (int j = 0; j < 4; j++) {
                float s = w2v[j] - 2.0f * acc[i][j][v];
                s = fminf(s, __shfl_xor(s, 1));
                s = fminf(s, __shfl_xor(s, 2));
                if ((cl & 3) == 0) grow[j * 4 + (cl >> 2)] = (_Float16)s;
            }
        }
}

// ---------------------------------------------------------------------------
// Fused epilogue: f16 group-min screen + 4-col-concurrent exact fp32 rescore
// (16 lanes/col, coalesced float4 W reads, order-preserving u64 min key)
// + uniform merge + separable Gaussian row write. (unchanged)
// ---------------------------------------------------------------------------
__global__ __launch_bounds__(256) void epilogue_kernel(
        const float* __restrict__ w2, const float* __restrict__ xnorm,
        const float* __restrict__ X, const float* __restrict__ W,
        const _Float16* __restrict__ gm,
        const int* __restrict__ decay_p, const int* __restrict__ it_p,
        float* __restrict__ out) {
    __shared__ float xs[512];
    __shared__ int   list[NGRP];
    __shared__ int   cnt;
    __shared__ float wmin[4];
    __shared__ unsigned long long wkey[4];
    __shared__ float tab[128];
    const int row  = blockIdx.x;
    const int t    = threadIdx.x;
    const int lane = t & 63;
    const int w    = t >> 6;

    {
        float2 xv = *(const float2*)(X + (size_t)row * DIMK + t * 2);
        xs[2 * t]     = xv.x;
        xs[2 * t + 1] = xv.y;
    }
    if (t == 0) cnt = 0;

    // f16 group-mins: 4 per thread (8B coalesced), packed 2KB/row
    half4_t gmh = *((const half4_t*)(gm + (size_t)row * 1024) + t);
    float gme[4] = {(float)gmh[0], (float)gmh[1], (float)gmh[2], (float)gmh[3]};
    float g = fminf(fminf(gme[0], gme[1]), fminf(gme[2], gme[3]));
#pragma unroll
    for (int mask = 1; mask <= 32; mask <<= 1)
        g = fminf(g, __shfl_xor(g, mask));
    if (lane == 0) wmin[w] = g;
    __syncthreads();
    const float gmin = fminf(fminf(wmin[0], wmin[1]), fminf(wmin[2], wmin[3]));
    const float tau  = gmin + 2.0f * (0.0222f * xnorm[row] + 0.25f);

#pragma unroll
    for (int e = 0; e < 4; e++)
        if (gme[e] <= tau) list[atomicAdd(&cnt, 1)] = t * 4 + e;
    __syncthreads();
    const int total = cnt;            // >= 1 always (gmin's group qualifies)

    // preload this lane's x-slice: float4 elems e*16 + s16, e = 0..7
    const int s16 = lane & 15;
    const int cg  = lane >> 4;        // column-in-group this lane serves
    float4 xq[8];
#pragma unroll
    for (int e = 0; e < 8; e++) xq[e] = ((const float4*)xs)[e * 16 + s16];

    unsigned long long mkey = ~0ULL;
    for (int idx = w; idx < total; idx += 4) {
        const int col = list[idx] * 4 + cg;
        const float4* wr = (const float4*)(W + (size_t)col * DIMK);
        float p = 0.f;
#pragma unroll
        for (int e = 0; e < 8; e++) {
            float4 wv = wr[e * 16 + s16];   // 16 lanes x 16B contiguous / col
            p += xq[e].x * wv.x + xq[e].y * wv.y
               + xq[e].z * wv.z + xq[e].w * wv.w;
        }
        p += __shfl_xor(p, 1); p += __shfl_xor(p, 2);
        p += __shfl_xor(p, 4); p += __shfl_xor(p, 8);
        const float s = w2[col] - 2.0f * p;
        unsigned int b = __float_as_uint(s);
        unsigned int u = (b & 0x80000000u) ? ~b : (b | 0x80000000u);
        unsigned long long key = ((unsigned long long)u << 32) | (unsigned int)col;
        mkey = key < mkey ? key : mkey;
    }
    {   // fold the 4 column-sets (lane bits 4,5)
        unsigned long long o;
        o = __shfl_xor(mkey, 16); mkey = o < mkey ? o : mkey;
        o = __shfl_xor(mkey, 32); mkey = o < mkey ? o : mkey;
    }
    if (lane == 0) wkey[w] = mkey;
    __syncthreads();
    // uniform merge: every thread computes the same winner
    unsigned long long k = wkey[0];
#pragma unroll
    for (int i = 1; i < 4; i++) k = wkey[i] < k ? wkey[i] : k;
    const int sbi = (int)(k & 0xffffffffu);

    // separable Gaussian tables + row write
    const float lr  = __expf(-(float)(*it_p) / (float)(*decay_p));
    const float so  = 32.0f * lr;          // SIGMA = 32
    const float inv = 1.0f / (so * so);
    const int rr = sbi >> 6, cc = sbi & 63;
    if (t < 64) {
        float d = (float)(t - rr);
        tab[t] = __expf(-d * d * inv);
    } else if (t < 128) {
        float d = (float)(t - 64 - cc);
        tab[t] = __expf(-d * d * inv);
    }
    __syncthreads();
    const float* er = tab;
    const float* ec = tab + 64;
    f32x4* orow = (f32x4*)(out + (size_t)row * 4096);
#pragma unroll
    for (int qq = 0; qq < 4; qq++) {
        int f  = qq * 256 + t;
        int i  = f >> 4;
        int j0 = (f & 15) * 4;
        float e = er[i];
        f32x4 o = {e * ec[j0], e * ec[j0 + 1], e * ec[j0 + 2], e * ec[j0 + 3]};
        __builtin_nontemporal_store(o, orow + f);
    }
}

// ---------------------------------------------------------------------------
extern "C" void kernel_launch(void* const* d_in, const int* in_sizes, int n_in,
                              void* d_out, int out_size, void* d_ws, size_t ws_size,
                              hipStream_t stream) {
    const float* X       = (const float*)d_in[0];   // [4096,512]
    const float* W       = (const float*)d_in[1];   // [4096,512]
    const int*   decay_p = (const int*)d_in[3];
    const int*   it_p    = (const int*)d_in[4];
    float* out = (float*)d_out;

    // ws: Xh 4MB | Wh 4MB | w2 16KB | xnorm 16KB | gmins 8MB
    _Float16* Xh = (_Float16*)d_ws;
    _Float16* Wh = Xh + (size_t)BATCH * DIMK;
    float*    w2 = (float*)(Wh + (size_t)MN * DIMK);
    float*    xn = w2 + MN;
    _Float16* gmv = (_Float16*)(xn + BATCH);

    convert_kernel<<<2048, 256, 0, stream>>>(X, W, Xh, Wh, w2, xn);
    score_kernel<<<dim3(32, 32), 256, 0, stream>>>(Xh, Wh, w2, gmv);
    epilogue_kernel<<<BATCH, 256, 0, stream>>>(w2, xn, X, W, gmv, decay_p, it_p, out);
}

// Round 7
// 128.958 us; speedup vs baseline: 1.2424x; 1.0389x over previous
//
#include <hip/hip_runtime.h>
#include <cfloat>

// Problem constants: M=N=64 grid, DIM=512, B=4096, SIGMA=32
#define DIMK 512
#define MN   4096
#define BATCH 4096
#define NGRP 1024   // 4-column groups per row

typedef _Float16 half8_t __attribute__((ext_vector_type(8)));
typedef _Float16 half4_t __attribute__((ext_vector_type(4)));
typedef float f32x4 __attribute__((ext_vector_type(4)));

// async global->LDS, 16B per lane; LDS dest is wave-uniform base + lane*16
#define GLD16(gp, lp) __builtin_amdgcn_global_load_lds( \
    (const __attribute__((address_space(1))) void*)(gp), \
    (__attribute__((address_space(3))) void*)(lp), 16, 0, 0)

// ---------------------------------------------------------------------------
// Convert: X,W fp32 -> f16 RTN + exact fp32 row norms. (unchanged)
// ---------------------------------------------------------------------------
__global__ __launch_bounds__(256) void convert_kernel(
        const float* __restrict__ X, const float* __restrict__ W,
        _Float16* __restrict__ Xh, _Float16* __restrict__ Wh,
        float* __restrict__ w2, float* __restrict__ xnorm) {
    const int blk  = blockIdx.x;
    const int t    = threadIdx.x;
    const bool isW = blk >= 1024;
    const float* src = isW ? W : X;
    _Float16* dst  = isW ? Wh : Xh;
    const int rblk = isW ? blk - 1024 : blk;
    const size_t idx = (size_t)rblk * 2048 + (size_t)t * 8;

    float4 v0 = *(const float4*)(src + idx);
    float4 v1 = *(const float4*)(src + idx + 4);
    float v[8] = {v0.x, v0.y, v0.z, v0.w, v1.x, v1.y, v1.z, v1.w};
    half8_t hv;
    float s = 0.f;
#pragma unroll
    for (int e = 0; e < 8; e++) {
        s += v[e] * v[e];
        hv[e] = (_Float16)v[e];
    }
    *(half8_t*)(dst + idx) = hv;
#pragma unroll
    for (int o = 32; o > 0; o >>= 1) s += __shfl_down(s, o);
    if ((t & 63) == 0) {
        int row = rblk * 4 + (t >> 6);
        if (isW) w2[row] = s;
        else     xnorm[row] = __fsqrt_rn(s);
    }
}

// ---------------------------------------------------------------------------
// Score GEMM v7: R6's coalesced+swizzled staging UNCHANGED, but occupancy
// 2 -> 4 blocks/CU (16 waves/CU) with the proven m97/T3-minimum 2-phase
// discipline: 2-deep ring (2 x 16 KiB = 32 KiB LDS), per K-tile
// {STAGE next -> ds_read cur -> lgkmcnt(0) -> 16 MFMA -> vmcnt(0) ->
// s_barrier}. The per-block vmcnt(0) drain is hidden by the other 3
// co-resident blocks (m114 cross-block MFMA/VALU/mem overlap) — the
// mechanism every 8-wave variant of R1-R6 lacked (MfmaUtil~VALUBusy~12%,
// all pipes idle = TLP starvation). Fragment reads, K-accumulation order,
// and tail are bit-identical to prior rounds -> identical group-mins.
// ---------------------------------------------------------------------------
__global__ __launch_bounds__(256, 4) void score_kernel(
        const _Float16* __restrict__ Xh, const _Float16* __restrict__ Wh,
        const float* __restrict__ w2, _Float16* __restrict__ Gm) {
    // slot = [A 4096 f16 (128 rows x 32)][B 4096] = 16 KiB; double-buffer.
    __shared__ __align__(16) _Float16 lds[2][8192];

    const int t    = threadIdx.x;
    const int lane = t & 63;
    const int w    = t >> 6;        // wave 0..3
    const int wm   = w >> 1;        // m-half (0..1) -> 64 rows
    const int wn   = w & 1;         // n-half (0..1) -> 64 cols

    // bijective XCD swizzle: 1024 blocks, 8 XCDs x 128; per XCD an
    // 8(bm) x 16(bn) rect -> working set A 1MB + B 2MB = 3MB < 4MB L2.
    const int id  = blockIdx.y * 32 + blockIdx.x;   // gridDim (32,32)
    const int xcd = id & 7;
    const int li  = id >> 3;                        // 0..127
    const int bm  = (xcd >> 1) * 8 + (li >> 4);     // 0..31
    const int bn  = (xcd & 1) * 16 + (li & 15);     // 0..31
    const int m0  = bm * 128;
    const int n0  = bn * 128;

    const _Float16* gA = Xh + (size_t)m0 * DIMK;
    const _Float16* gB = Wh + (size_t)n0 * DIMK;

    // staging source (per-lane, f16 units): row-in-group = lane>>2,
    // source chunk = (lane&3) ^ x(row), x(row) = (lane>>3)&3.
    // Lanes 0-3 read contiguous 64B of one row (permuted 16B chunks)
    // -> 16 cache lines per gld_lds instead of 64.
    const int soff = (lane >> 2) * DIMK + (((lane & 3) ^ ((lane >> 3) & 3)) * 8);

    // STG(reg, rb, kt, sl): stage rows [rb, rb+16) of region reg, k-slice kt,
    // into buffer sl. LDS dest is wave-uniform (HW adds lane*16B).
#define STG(reg, rb, kt, sl) GLD16( \
    ((reg) ? gB : gA) + (size_t)(rb) * DIMK + (kt) * 32 + soff, \
    &lds[sl][(reg) * 4096 + (rb) * 32])

    // fragment ds_read addr: row = half*64 + rg*16 + r16, chunk = kg ^ x(row);
    // x(row) reduces to (r16>>1)&3.
    const int r16 = lane & 15;
    const int kg  = lane >> 4;
    const int xx  = (r16 >> 1) & 3;
    const int aoff =        wm * 2048 + r16 * 32 + ((kg ^ xx) * 8);
    const int boff = 4096 + wn * 2048 + r16 * 32 + ((kg ^ xx) * 8);

#define LDA(sl, rg) (*(const half8_t*)(&lds[sl][aoff + (rg) * 512]))
#define LDB(sl, rg) (*(const half8_t*)(&lds[sl][boff + (rg) * 512]))

    f32x4 acc[4][4];
#pragma unroll
    for (int i = 0; i < 4; i++)
#pragma unroll
        for (int j = 0; j < 4; j++) acc[i][j] = (f32x4){0.f, 0.f, 0.f, 0.f};

    const int w32 = w * 32;
    // prologue: stage tile 0 into buffer 0, drain, sync
    STG(0, w32,      0, 0);
    STG(0, w32 + 16, 0, 0);
    STG(1, w32,      0, 0);
    STG(1, w32 + 16, 0, 0);
    asm volatile("s_waitcnt vmcnt(0)" ::: "memory");
    __builtin_amdgcn_s_barrier();

#pragma unroll
    for (int kt = 0; kt < 16; ++kt) {
        const int sl = kt & 1;
        const int nx = sl ^ 1;

        // issue next tile's 4 loads into the other buffer (safe: all waves
        // finished reading it before the barrier that ended iter kt-1)
        if (kt < 15) {
            STG(0, w32,      kt + 1, nx);
            STG(0, w32 + 16, kt + 1, nx);
            STG(1, w32,      kt + 1, nx);
            STG(1, w32 + 16, kt + 1, nx);
        }

        half8_t a0 = LDA(sl, 0), a1 = LDA(sl, 1);
        half8_t a2 = LDA(sl, 2), a3 = LDA(sl, 3);
        half8_t b0 = LDB(sl, 0), b1 = LDB(sl, 1);
        half8_t b2 = LDB(sl, 2), b3 = LDB(sl, 3);

        asm volatile("s_waitcnt lgkmcnt(0)" ::: "memory");
        __builtin_amdgcn_sched_barrier(0);
        __builtin_amdgcn_s_setprio(1);
#pragma unroll
        for (int i = 0; i < 4; i++) {
            half8_t av = (i == 0) ? a0 : (i == 1) ? a1 : (i == 2) ? a2 : a3;
            acc[i][0] = __builtin_amdgcn_mfma_f32_16x16x32_f16(av, b0, acc[i][0], 0, 0, 0);
            acc[i][1] = __builtin_amdgcn_mfma_f32_16x16x32_f16(av, b1, acc[i][1], 0, 0, 0);
            acc[i][2] = __builtin_amdgcn_mfma_f32_16x16x32_f16(av, b2, acc[i][2], 0, 0, 0);
            acc[i][3] = __builtin_amdgcn_mfma_f32_16x16x32_f16(av, b3, acc[i][3], 0, 0, 0);
        }
        __builtin_amdgcn_s_setprio(0);

        // end-gate: next tile landed (own 4 loads drained) AND all waves'
        // reads of buffer sl complete -> iter kt+1 may stage into sl.
        asm volatile("s_waitcnt vmcnt(0)" ::: "memory");
        __builtin_amdgcn_sched_barrier(0);
        __builtin_amdgcn_s_barrier();
    }

    // ---- 4-col group mins -> f16, packed 1024/row (verified layout).
    // D layout: col=lane&15, row=(lane>>4)*4+v ----
    const int q   = lane >> 4;
    const int cl  = lane & 15;
    const int gb  = (n0 >> 2) + wn * 16;
    float w2v[4];
#pragma unroll
    for (int j = 0; j < 4; j++) w2v[j] = w2[n0 + wn * 64 + j * 16 + cl];
#pragma unroll
    for (int i = 0; i < 4; i++)
#pragma unroll
        for (int v = 0; v < 4; v++) {
            const int row = m0 + wm * 64 + i * 16 + q * 4 + v;
            _Float16* grow = Gm + (size_t)row * 1024 + gb;
#pragma unroll
            for (int j = 0; j < 4; j++) {
                float s = w2v[j] - 2.0f * acc[i][j][v];
                s = fminf(s, __shfl_xor(s, 1));
                s = fminf(s, __shfl_xor(s, 2));
                if ((cl & 3) == 0) grow[j * 4 + (cl >> 2)] = (_Float16)s;
            }
        }
}

// ---------------------------------------------------------------------------
// Fused epilogue: f16 group-min screen + 4-col-concurrent exact fp32 rescore
// (16 lanes/col, coalesced float4 W reads, order-preserving u64 min key)
// + uniform merge + separable Gaussian row write. (unchanged)
// ---------------------------------------------------------------------------
__global__ __launch_bounds__(256) void epilogue_kernel(
        const float* __restrict__ w2, const float* __restrict__ xnorm,
        const float* __restrict__ X, const float* __restrict__ W,
        const _Float16* __restrict__ gm,
        const int* __restrict__ decay_p, const int* __restrict__ it_p,
        float* __restrict__ out) {
    __shared__ float xs[512];
    __shared__ int   list[NGRP];
    __shared__ int   cnt;
    __shared__ float wmin[4];
    __shared__ unsigned long long wkey[4];
    __shared__ float tab[128];
    const int row  = blockIdx.x;
    const int t    = threadIdx.x;
    const int lane = t & 63;
    const int w    = t >> 6;

    {
        float2 xv = *(const float2*)(X + (size_t)row * DIMK + t * 2);
        xs[2 * t]     = xv.x;
        xs[2 * t + 1] = xv.y;
    }
    if (t == 0) cnt = 0;

    // f16 group-mins: 4 per thread (8B coalesced), packed 2KB/row
    half4_t gmh = *((const half4_t*)(gm + (size_t)row * 1024) + t);
    float gme[4] = {(float)gmh[0], (float)gmh[1], (float)gmh[2], (float)gmh[3]};
    float g = fminf(fminf(gme[0], gme[1]), fminf(gme[2], gme[3]));
#pragma unroll
    for (int mask = 1; mask <= 32; mask <<= 1)
        g = fminf(g, __shfl_xor(g, mask));
    if (lane == 0) wmin[w] = g;
    __syncthreads();
    const float gmin = fminf(fminf(wmin[0], wmin[1]), fminf(wmin[2], wmin[3]));
    const float tau  = gmin + 2.0f * (0.0222f * xnorm[row] + 0.25f);

#pragma unroll
    for (int e = 0; e < 4; e++)
        if (gme[e] <= tau) list[atomicAdd(&cnt, 1)] = t * 4 + e;
    __syncthreads();
    const int total = cnt;            // >= 1 always (gmin's group qualifies)

    // preload this lane's x-slice: float4 elems e*16 + s16, e = 0..7
    const int s16 = lane & 15;
    const int cg  = lane >> 4;        // column-in-group this lane serves
    float4 xq[8];
#pragma unroll
    for (int e = 0; e < 8; e++) xq[e] = ((const float4*)xs)[e * 16 + s16];

    unsigned long long mkey = ~0ULL;
    for (int idx = w; idx < total; idx += 4) {
        const int col = list[idx] * 4 + cg;
        const float4* wr = (const float4*)(W + (size_t)col * DIMK);
        float p = 0.f;
#pragma unroll
        for (int e = 0; e < 8; e++) {
            float4 wv = wr[e * 16 + s16];   // 16 lanes x 16B contiguous / col
            p += xq[e].x * wv.x + xq[e].y * wv.y
               + xq[e].z * wv.z + xq[e].w * wv.w;
        }
        p += __shfl_xor(p, 1); p += __shfl_xor(p, 2);
        p += __shfl_xor(p, 4); p += __shfl_xor(p, 8);
        const float s = w2[col] - 2.0f * p;
        unsigned int b = __float_as_uint(s);
        unsigned int u = (b & 0x80000000u) ? ~b : (b | 0x80000000u);
        unsigned long long key = ((unsigned long long)u << 32) | (unsigned int)col;
        mkey = key < mkey ? key : mkey;
    }
    {   // fold the 4 column-sets (lane bits 4,5)
        unsigned long long o;
        o = __shfl_xor(mkey, 16); mkey = o < mkey ? o : mkey;
        o = __shfl_xor(mkey, 32); mkey = o < mkey ? o : mkey;
    }
    if (lane == 0) wkey[w] = mkey;
    __syncthreads();
    // uniform merge: every thread computes the same winner
    unsigned long long k = wkey[0];
#pragma unroll
    for (int i = 1; i < 4; i++) k = wkey[i] < k ? wkey[i] : k;
    const int sbi = (int)(k & 0xffffffffu);

    // separable Gaussian tables + row write
    const float lr  = __expf(-(float)(*it_p) / (float)(*decay_p));
    const float so  = 32.0f * lr;          // SIGMA = 32
    const float inv = 1.0f / (so * so);
    const int rr = sbi >> 6, cc = sbi & 63;
    if (t < 64) {
        float d = (float)(t - rr);
        tab[t] = __expf(-d * d * inv);
    } else if (t < 128) {
        float d = (float)(t - 64 - cc);
        tab[t] = __expf(-d * d * inv);
    }
    __syncthreads();
    const float* er = tab;
    const float* ec = tab + 64;
    f32x4* orow = (f32x4*)(out + (size_t)row * 4096);
#pragma unroll
    for (int qq = 0; qq < 4; qq++) {
        int f  = qq * 256 + t;
        int i  = f >> 4;
        int j0 = (f & 15) * 4;
        float e = er[i];
        f32x4 o = {e * ec[j0], e * ec[j0 + 1], e * ec[j0 + 2], e * ec[j0 + 3]};
        __builtin_nontemporal_store(o, orow + f);
    }
}

// ---------------------------------------------------------------------------
extern "C" void kernel_launch(void* const* d_in, const int* in_sizes, int n_in,
                              void* d_out, int out_size, void* d_ws, size_t ws_size,
                              hipStream_t stream) {
    const float* X       = (const float*)d_in[0];   // [4096,512]
    const float* W       = (const float*)d_in[1];   // [4096,512]
    const int*   decay_p = (const int*)d_in[3];
    const int*   it_p    = (const int*)d_in[4];
    float* out = (float*)d_out;

    // ws: Xh 4MB | Wh 4MB | w2 16KB | xnorm 16KB | gmins 8MB
    _Float16* Xh = (_Float16*)d_ws;
    _Float16* Wh = Xh + (size_t)BATCH * DIMK;
    float*    w2 = (float*)(Wh + (size_t)MN * DIMK);
    float*    xn = w2 + MN;
    _Float16* gmv = (_Float16*)(xn + BATCH);

    convert_kernel<<<2048, 256, 0, stream>>>(X, W, Xh, Wh, w2, xn);
    score_kernel<<<dim3(32, 32), 256, 0, stream>>>(Xh, Wh, w2, gmv);
    epilogue_kernel<<<BATCH, 256, 0, stream>>>(w2, xn, X, W, gmv, decay_p, it_p, out);
}